// Round 1
// baseline (24791.110 us; speedup 1.0000x reference)
//
#include <hip/hip_runtime.h>
#include <math.h>

#define DD 64

// out[tgt[e]] += val[e] * in[src[e]]  (COO SpMM, 16 threads/edge, float4 chunks)
__global__ void spmm_kernel(float* __restrict__ out, const float* __restrict__ in,
                            const int* __restrict__ tgt, const int* __restrict__ src,
                            const float* __restrict__ val, long long nwork) {
    long long g = (long long)blockIdx.x * blockDim.x + threadIdx.x;
    long long stride = (long long)gridDim.x * blockDim.x;
    for (long long t = g; t < nwork; t += stride) {
        int e = (int)(t >> 4);
        int c = (int)(t & 15);
        int s = src[e];
        int dt = tgt[e];
        float v = val[e];
        float4 x = ((const float4*)(in + (size_t)s * DD))[c];
        float* o = out + (size_t)dt * DD + (size_t)c * 4;
        unsafeAtomicAdd(o + 0, v * x.x);
        unsafeAtomicAdd(o + 1, v * x.y);
        unsafeAtomicAdd(o + 2, v * x.z);
        unsafeAtomicAdd(o + 3, v * x.w);
    }
}

// io = (a + b + io) / 3
__global__ void avg3_kernel(float4* __restrict__ io, const float4* __restrict__ a,
                            const float4* __restrict__ b, long long n4) {
    long long g = (long long)blockIdx.x * blockDim.x + threadIdx.x;
    long long stride = (long long)gridDim.x * blockDim.x;
    const float k = 1.0f / 3.0f;
    for (long long i = g; i < n4; i += stride) {
        float4 x = io[i], y = a[i], z = b[i];
        x.x = (x.x + y.x + z.x) * k;
        x.y = (x.y + y.y + z.y) * k;
        x.z = (x.z + y.z + z.z) * k;
        x.w = (x.w + y.w + z.w) * k;
        io[i] = x;
    }
}

// out[r*64+d] = src[idx[r]*64+d]
__global__ void gather_kernel(float* __restrict__ out, const float* __restrict__ src,
                              const int* __restrict__ idx, int nrows) {
    int g = blockIdx.x * blockDim.x + threadIdx.x;
    if (g >= nrows * DD) return;
    int r = g >> 6;
    out[g] = src[(size_t)idx[r] * DD + (g & 63)];
}

// out[r] = normalize(src[idx[r*istride]])   (row L2-normalize, 1 wave/row)
__global__ void gather_norm_kernel(float* __restrict__ out, const float* __restrict__ src,
                                   const int* __restrict__ idx, int nrows, int istride) {
    int r = blockIdx.x;
    if (r >= nrows) return;
    int d = threadIdx.x;
    float v = src[(size_t)idx[(size_t)r * istride] * DD + d];
    float ss = v * v;
#pragma unroll
    for (int o = 32; o >= 1; o >>= 1) ss += __shfl_xor(ss, o);
    out[(size_t)r * DD + d] = v * rsqrtf(ss + 1e-8f);
}

// per-batch-element: 6 dots -> 3->3->3->1 tanh MLP -> BPR softplus, atomic acc
__global__ void batch_pred_kernel(const float* __restrict__ u1, const float* __restrict__ u2,
                                  const float* __restrict__ u3b,
                                  const float* __restrict__ b1, const float* __restrict__ b2,
                                  const float* __restrict__ b3,
                                  const int* __restrict__ uidx, const int* __restrict__ bidx,
                                  const float* __restrict__ W1, const float* __restrict__ c1,
                                  const float* __restrict__ W2, const float* __restrict__ c2,
                                  const float* __restrict__ W3, const float* __restrict__ c3,
                                  float* __restrict__ acc, int nb) {
    int b = blockIdx.x;
    if (b >= nb) return;
    int d = threadIdx.x;
    int u = uidx[b];
    float ud1 = u1[(size_t)u * DD + d];
    float ud2 = u2[(size_t)u * DD + d];
    float ud3 = u3b[(size_t)b * DD + d];
    float pred[2];
#pragma unroll
    for (int p = 0; p < 2; ++p) {
        int bi = bidx[b * 2 + p];
        float s0 = ud1 * b1[(size_t)bi * DD + d];
        float s1 = ud2 * b2[(size_t)bi * DD + d];
        float s2 = ud3 * b3[(size_t)bi * DD + d];
#pragma unroll
        for (int o = 32; o >= 1; o >>= 1) {
            s0 += __shfl_xor(s0, o);
            s1 += __shfl_xor(s1, o);
            s2 += __shfl_xor(s2, o);
        }
        float t0 = tanhf(s0 * W1[0] + s1 * W1[1] + s2 * W1[2] + c1[0]);
        float t1 = tanhf(s0 * W1[3] + s1 * W1[4] + s2 * W1[5] + c1[1]);
        float t2 = tanhf(s0 * W1[6] + s1 * W1[7] + s2 * W1[8] + c1[2]);
        float g0 = tanhf(t0 * W2[0] + t1 * W2[1] + t2 * W2[2] + c2[0]);
        float g1 = tanhf(t0 * W2[3] + t1 * W2[4] + t2 * W2[5] + c2[1]);
        float g2 = tanhf(t0 * W2[6] + t1 * W2[7] + t2 * W2[8] + c2[2]);
        pred[p] = g0 * W3[0] + g1 * W3[1] + g2 * W3[2] + c3[0];
    }
    if (d == 0) {
        float x = pred[1] - pred[0];  // softplus(neg - pos)
        float sp = (x > 20.0f) ? x : log1pf(expf(x));
        unsafeAtomicAdd(acc, sp);
    }
}

// per row i: logsumexp_j(A_i . B_j / temp) - diag, online over column tiles of 64
__global__ void nce_kernel(const float* __restrict__ A, const float* __restrict__ B,
                           float* __restrict__ acc, int n, float invtemp) {
    __shared__ float4 a_lds[4][16];
    int wv = threadIdx.x >> 6;
    int lane = threadIdx.x & 63;
    int row = blockIdx.x * 4 + wv;
    if (lane < 16) a_lds[wv][lane] = ((const float4*)(A + (size_t)row * DD))[lane];
    __syncthreads();
    float m = -1e30f, ssum = 0.0f, diag = 0.0f;
    int ntile = n >> 6;
    for (int t = 0; t < ntile; ++t) {
        int j = (t << 6) + lane;
        const float4* Bj = (const float4*)(B + (size_t)j * DD);
        float dot = 0.0f;
#pragma unroll
        for (int q = 0; q < 16; ++q) {
            float4 a4 = a_lds[wv][q];
            float4 b4 = Bj[q];
            dot += a4.x * b4.x + a4.y * b4.y + a4.z * b4.z + a4.w * b4.w;
        }
        float lg = dot * invtemp;
        if (j == row) diag = lg;
        float mn = fmaxf(m, lg);
        ssum = ssum * __expf(m - mn) + __expf(lg - mn);
        m = mn;
    }
#pragma unroll
    for (int o = 32; o >= 1; o >>= 1) {
        float m2 = __shfl_xor(m, o);
        float s2 = __shfl_xor(ssum, o);
        float d2 = __shfl_xor(diag, o);
        float mn = fmaxf(m, m2);
        ssum = ssum * __expf(m - mn) + s2 * __expf(m2 - mn);
        m = mn;
        diag += d2;
    }
    if (lane == 0) unsafeAtomicAdd(acc, m + logf(ssum) - diag);
}

__global__ void final_kernel(const float* __restrict__ acc, float* __restrict__ out,
                             float invn, float alpha) {
    out[0] = acc[0] * invn + alpha * invn * (acc[1] + acc[2]);
}

extern "C" void kernel_launch(void* const* d_in, const int* in_sizes, int n_in,
                              void* d_out, int out_size, void* d_ws, size_t ws_size,
                              hipStream_t stream) {
    const float* users_feat   = (const float*)d_in[0];
    const float* bundles_feat = (const float*)d_in[1];
    const float* items_feat   = (const float*)d_in[2];
    const float* W1 = (const float*)d_in[3];
    const float* c1 = (const float*)d_in[4];
    const float* W2 = (const float*)d_in[5];
    const float* c2 = (const float*)d_in[6];
    const float* W3 = (const float*)d_in[7];
    const float* c3 = (const float*)d_in[8];
    const float* ui_val = (const float*)d_in[9];
    const float* ub_val = (const float*)d_in[10];
    const float* bi_val = (const float*)d_in[11];
    const int* ui_row = (const int*)d_in[12];
    const int* ui_col = (const int*)d_in[13];
    const int* ub_row = (const int*)d_in[14];
    const int* ub_col = (const int*)d_in[15];
    const int* bi_row = (const int*)d_in[16];
    const int* bi_col = (const int*)d_in[17];
    const int* uidx = (const int*)d_in[18];
    const int* bidx = (const int*)d_in[19];

    const int U  = in_sizes[0] / DD;
    const int NB = in_sizes[1] / DD;
    const int I  = in_sizes[2] / DD;
    const int Eui = in_sizes[9];
    const int Eub = in_sizes[10];
    const int Ebi = in_sizes[11];
    const int BT = in_sizes[18];

    float* w = (float*)d_ws;
    size_t o = 0;
    float* bufA = w + o; o += (size_t)U * DD;   // x1a / y1a  (x1a == u3 full)
    float* bufB = w + o; o += (size_t)I * DD;   // x1b / y1b / b3
    float* u1   = w + o; o += (size_t)U * DD;   // x2a -> u1
    float* i1   = w + o; o += (size_t)I * DD;   // x2b -> i1
    float* b1   = w + o; o += (size_t)NB * DD;
    float* u2   = w + o; o += (size_t)U * DD;   // y2a -> u2
    float* b2   = w + o; o += (size_t)NB * DD;  // y2b -> b2
    float* u3b  = w + o; o += (size_t)BT * DD;
    float* A1   = w + o; o += (size_t)BT * DD;
    float* A2   = w + o; o += (size_t)BT * DD;
    float* B1n  = w + o; o += (size_t)BT * DD;
    float* B2n  = w + o; o += (size_t)BT * DD;
    float* acc  = w + o; o += 4;

    const size_t Ub  = (size_t)U * DD * sizeof(float);
    const size_t Ib  = (size_t)I * DD * sizeof(float);
    const size_t NBb = (size_t)NB * DD * sizeof(float);

    auto spmm = [&](float* out_, const float* in_, const int* tgt, const int* src,
                    const float* val, int E) {
        long long nwork = (long long)E * 16;
        long long nb_ = (nwork + 255) / 256;
        int blocks = (int)(nb_ > 16384 ? 16384 : nb_);
        spmm_kernel<<<blocks, 256, 0, stream>>>(out_, in_, tgt, src, val, nwork);
    };
    auto avg3 = [&](float* io, const float* a, const float* b, long long n) {
        long long n4 = n / 4;
        long long nb_ = (n4 + 255) / 256;
        int blocks = (int)(nb_ > 4096 ? 4096 : nb_);
        avg3_kernel<<<blocks, 256, 0, stream>>>((float4*)io, (const float4*)a,
                                                (const float4*)b, n4);
    };

    // ---- View 1: u-i propagation (2 layers) ----
    hipMemsetAsync(bufA, 0, Ub, stream);
    hipMemsetAsync(bufB, 0, Ib, stream);
    hipMemsetAsync(u1, 0, Ub, stream);
    hipMemsetAsync(i1, 0, Ib, stream);
    spmm(bufA, items_feat, ui_row, ui_col, ui_val, Eui);   // x1a (== u3)
    spmm(bufB, users_feat, ui_col, ui_row, ui_val, Eui);   // x1b
    spmm(u1, bufB, ui_row, ui_col, ui_val, Eui);           // x2a
    spmm(i1, bufA, ui_col, ui_row, ui_val, Eui);           // x2b
    // grab u3 batch rows from x1a before buffer reuse
    {
        int nthr = BT * DD;
        gather_kernel<<<(nthr + 255) / 256, 256, 0, stream>>>(u3b, bufA, uidx, BT);
    }
    avg3(u1, users_feat, bufA, (long long)U * DD);         // u1 = (x0+x1+x2)/3
    avg3(i1, items_feat, bufB, (long long)I * DD);         // i1
    // b1 = segsum(bi, i1)
    hipMemsetAsync(b1, 0, NBb, stream);
    spmm(b1, i1, bi_row, bi_col, bi_val, Ebi);

    // ---- View 2: u-b propagation (2 layers) ----
    hipMemsetAsync(bufA, 0, Ub, stream);
    hipMemsetAsync(bufB, 0, NBb, stream);
    spmm(bufA, bundles_feat, ub_row, ub_col, ub_val, Eub); // y1a
    spmm(bufB, users_feat, ub_col, ub_row, ub_val, Eub);   // y1b
    hipMemsetAsync(u2, 0, Ub, stream);
    hipMemsetAsync(b2, 0, NBb, stream);
    spmm(u2, bufB, ub_row, ub_col, ub_val, Eub);           // y2a
    spmm(b2, bufA, ub_col, ub_row, ub_val, Eub);           // y2b
    avg3(u2, users_feat, bufA, (long long)U * DD);
    avg3(b2, bundles_feat, bufB, (long long)NB * DD);

    // ---- View 3: b3 (u3 already captured) ----
    hipMemsetAsync(bufB, 0, NBb, stream);
    spmm(bufB, items_feat, bi_row, bi_col, bi_val, Ebi);   // b3

    // ---- batch gathers + normalized views for InfoNCE ----
    gather_norm_kernel<<<BT, 64, 0, stream>>>(A1, u1, uidx, BT, 1);
    gather_norm_kernel<<<BT, 64, 0, stream>>>(A2, u2, uidx, BT, 1);
    gather_norm_kernel<<<BT, 64, 0, stream>>>(B1n, b1, bidx, BT, 2);
    gather_norm_kernel<<<BT, 64, 0, stream>>>(B2n, b2, bidx, BT, 2);

    hipMemsetAsync(acc, 0, 4 * sizeof(float), stream);

    batch_pred_kernel<<<BT, 64, 0, stream>>>(u1, u2, u3b, b1, b2, bufB, uidx, bidx,
                                             W1, c1, W2, c2, W3, c3, acc, BT);

    nce_kernel<<<BT / 4, 256, 0, stream>>>(A1, A2, acc + 1, BT, 4.0f);   // 1/0.25
    nce_kernel<<<BT / 4, 256, 0, stream>>>(B1n, B2n, acc + 2, BT, 4.0f);

    final_kernel<<<1, 1, 0, stream>>>(acc, (float*)d_out, 1.0f / (float)BT, 0.5f);
}

// Round 2
// 24785.085 us; speedup vs baseline: 1.0002x; 1.0002x over previous
//
#include <hip/hip_runtime.h>
#include <math.h>

#define DD 64

// ============================ CSR build kernels ============================

__global__ void hist_kernel(int* __restrict__ cnt, const int* __restrict__ tgt, int E) {
    int g = blockIdx.x * blockDim.x + threadIdx.x;
    int stride = gridDim.x * blockDim.x;
    for (int e = g; e < E; e += stride) atomicAdd(&cnt[tgt[e]], 1);
}

// exclusive scan of cnt[0..n) -> ptr[0..n], single block of 1024 threads
__global__ void scan_kernel(int* __restrict__ ptr, const int* __restrict__ cnt, int n) {
    __shared__ int part[1024];
    int t = threadIdx.x;
    int per = (n + 1023) / 1024;
    int lo = t * per;
    int hi = lo + per; if (hi > n) hi = n;
    int s = 0;
    for (int i = lo; i < hi; ++i) s += cnt[i];
    part[t] = s;
    __syncthreads();
    for (int off = 1; off < 1024; off <<= 1) {
        int v = (t >= off) ? part[t - off] : 0;
        __syncthreads();
        part[t] += v;
        __syncthreads();
    }
    int run = (t == 0) ? 0 : part[t - 1];
    for (int i = lo; i < hi; ++i) { ptr[i] = run; run += cnt[i]; }
    if (t == 1023) ptr[n] = run;
}

__global__ void copy_int_kernel(int* __restrict__ dst, const int* __restrict__ src, int n) {
    int g = blockIdx.x * blockDim.x + threadIdx.x;
    if (g < n) dst[g] = src[g];
}

// pairs[pos] = (src[e], val[e]) grouped by tgt[e]; cursor pre-loaded with ptr
__global__ void scatter_kernel(int2* __restrict__ pairs, int* __restrict__ cursor,
                               const int* __restrict__ tgt, const int* __restrict__ src,
                               const float* __restrict__ val, int E) {
    int g = blockIdx.x * blockDim.x + threadIdx.x;
    int stride = gridDim.x * blockDim.x;
    for (int e = g; e < E; e += stride) {
        int t_ = tgt[e];
        int p = atomicAdd(&cursor[t_], 1);
        int2 pr;
        pr.x = src[e];
        pr.y = __float_as_int(val[e]);
        pairs[p] = pr;
    }
}

// ======================= gather-based segmented SpMM =======================
// one wave per output row; lane = dim; out[r] = sum_{e in row r} val_e * in[src_e]
__global__ void spmm_csr_kernel(float* __restrict__ out, const float* __restrict__ in,
                                const int2* __restrict__ pairs, const int* __restrict__ ptr,
                                int nrows) {
    int w = (int)((blockIdx.x * blockDim.x + threadIdx.x) >> 6);
    int lane = threadIdx.x & 63;
    if (w >= nrows) return;
    int p = ptr[w], end = ptr[w + 1];
    float acc0 = 0.0f, acc1 = 0.0f;
    for (; p + 1 < end; p += 2) {
        int2 a = pairs[p];
        int2 b = pairs[p + 1];
        int sa = __builtin_amdgcn_readfirstlane(a.x);
        float va = __int_as_float(__builtin_amdgcn_readfirstlane(a.y));
        int sb = __builtin_amdgcn_readfirstlane(b.x);
        float vb = __int_as_float(__builtin_amdgcn_readfirstlane(b.y));
        acc0 += va * in[(size_t)sa * DD + lane];
        acc1 += vb * in[(size_t)sb * DD + lane];
    }
    if (p < end) {
        int2 a = pairs[p];
        int sa = __builtin_amdgcn_readfirstlane(a.x);
        float va = __int_as_float(__builtin_amdgcn_readfirstlane(a.y));
        acc0 += va * in[(size_t)sa * DD + lane];
    }
    out[(size_t)w * DD + lane] = acc0 + acc1;
}

// ===================== fallback atomic SpMM (old path) =====================
__global__ void spmm_kernel(float* __restrict__ out, const float* __restrict__ in,
                            const int* __restrict__ tgt, const int* __restrict__ src,
                            const float* __restrict__ val, long long nwork) {
    long long g = (long long)blockIdx.x * blockDim.x + threadIdx.x;
    long long stride = (long long)gridDim.x * blockDim.x;
    for (long long t = g; t < nwork; t += stride) {
        int e = (int)(t >> 4);
        int c = (int)(t & 15);
        int s = src[e];
        int dt = tgt[e];
        float v = val[e];
        float4 x = ((const float4*)(in + (size_t)s * DD))[c];
        float* o = out + (size_t)dt * DD + (size_t)c * 4;
        unsafeAtomicAdd(o + 0, v * x.x);
        unsafeAtomicAdd(o + 1, v * x.y);
        unsafeAtomicAdd(o + 2, v * x.z);
        unsafeAtomicAdd(o + 3, v * x.w);
    }
}

// ============================= dense helpers ==============================

__global__ void avg3_kernel(float4* __restrict__ io, const float4* __restrict__ a,
                            const float4* __restrict__ b, long long n4) {
    long long g = (long long)blockIdx.x * blockDim.x + threadIdx.x;
    long long stride = (long long)gridDim.x * blockDim.x;
    const float k = 1.0f / 3.0f;
    for (long long i = g; i < n4; i += stride) {
        float4 x = io[i], y = a[i], z = b[i];
        x.x = (x.x + y.x + z.x) * k;
        x.y = (x.y + y.y + z.y) * k;
        x.z = (x.z + y.z + z.z) * k;
        x.w = (x.w + y.w + z.w) * k;
        io[i] = x;
    }
}

__global__ void gather_kernel(float* __restrict__ out, const float* __restrict__ src,
                              const int* __restrict__ idx, int nrows) {
    int g = blockIdx.x * blockDim.x + threadIdx.x;
    if (g >= nrows * DD) return;
    int r = g >> 6;
    out[g] = src[(size_t)idx[r] * DD + (g & 63)];
}

__global__ void gather_norm_kernel(float* __restrict__ out, const float* __restrict__ src,
                                   const int* __restrict__ idx, int nrows, int istride) {
    int r = blockIdx.x;
    if (r >= nrows) return;
    int d = threadIdx.x;
    float v = src[(size_t)idx[(size_t)r * istride] * DD + d];
    float ss = v * v;
#pragma unroll
    for (int o = 32; o >= 1; o >>= 1) ss += __shfl_xor(ss, o);
    out[(size_t)r * DD + d] = v * rsqrtf(ss + 1e-8f);
}

__global__ void batch_pred_kernel(const float* __restrict__ u1, const float* __restrict__ u2,
                                  const float* __restrict__ u3b,
                                  const float* __restrict__ b1, const float* __restrict__ b2,
                                  const float* __restrict__ b3,
                                  const int* __restrict__ uidx, const int* __restrict__ bidx,
                                  const float* __restrict__ W1, const float* __restrict__ c1,
                                  const float* __restrict__ W2, const float* __restrict__ c2,
                                  const float* __restrict__ W3, const float* __restrict__ c3,
                                  float* __restrict__ acc, int nb) {
    int b = blockIdx.x;
    if (b >= nb) return;
    int d = threadIdx.x;
    int u = uidx[b];
    float ud1 = u1[(size_t)u * DD + d];
    float ud2 = u2[(size_t)u * DD + d];
    float ud3 = u3b[(size_t)b * DD + d];
    float pred[2];
#pragma unroll
    for (int p = 0; p < 2; ++p) {
        int bi = bidx[b * 2 + p];
        float s0 = ud1 * b1[(size_t)bi * DD + d];
        float s1 = ud2 * b2[(size_t)bi * DD + d];
        float s2 = ud3 * b3[(size_t)bi * DD + d];
#pragma unroll
        for (int o = 32; o >= 1; o >>= 1) {
            s0 += __shfl_xor(s0, o);
            s1 += __shfl_xor(s1, o);
            s2 += __shfl_xor(s2, o);
        }
        float t0 = tanhf(s0 * W1[0] + s1 * W1[1] + s2 * W1[2] + c1[0]);
        float t1 = tanhf(s0 * W1[3] + s1 * W1[4] + s2 * W1[5] + c1[1]);
        float t2 = tanhf(s0 * W1[6] + s1 * W1[7] + s2 * W1[8] + c1[2]);
        float g0 = tanhf(t0 * W2[0] + t1 * W2[1] + t2 * W2[2] + c2[0]);
        float g1 = tanhf(t0 * W2[3] + t1 * W2[4] + t2 * W2[5] + c2[1]);
        float g2 = tanhf(t0 * W2[6] + t1 * W2[7] + t2 * W2[8] + c2[2]);
        pred[p] = g0 * W3[0] + g1 * W3[1] + g2 * W3[2] + c3[0];
    }
    if (d == 0) {
        float x = pred[1] - pred[0];
        float sp = (x > 20.0f) ? x : log1pf(expf(x));
        unsafeAtomicAdd(acc, sp);
    }
}

__global__ void nce_kernel(const float* __restrict__ A, const float* __restrict__ B,
                           float* __restrict__ acc, int n, float invtemp) {
    __shared__ float4 a_lds[4][16];
    int wv = threadIdx.x >> 6;
    int lane = threadIdx.x & 63;
    int row = blockIdx.x * 4 + wv;
    if (lane < 16) a_lds[wv][lane] = ((const float4*)(A + (size_t)row * DD))[lane];
    __syncthreads();
    float m = -1e30f, ssum = 0.0f, diag = 0.0f;
    int ntile = n >> 6;
    for (int t = 0; t < ntile; ++t) {
        int j = (t << 6) + lane;
        const float4* Bj = (const float4*)(B + (size_t)j * DD);
        float dot = 0.0f;
#pragma unroll
        for (int q = 0; q < 16; ++q) {
            float4 a4 = a_lds[wv][q];
            float4 b4 = Bj[q];
            dot += a4.x * b4.x + a4.y * b4.y + a4.z * b4.z + a4.w * b4.w;
        }
        float lg = dot * invtemp;
        if (j == row) diag = lg;
        float mn = fmaxf(m, lg);
        ssum = ssum * __expf(m - mn) + __expf(lg - mn);
        m = mn;
    }
#pragma unroll
    for (int o = 32; o >= 1; o >>= 1) {
        float m2 = __shfl_xor(m, o);
        float s2 = __shfl_xor(ssum, o);
        float d2 = __shfl_xor(diag, o);
        float mn = fmaxf(m, m2);
        ssum = ssum * __expf(m - mn) + s2 * __expf(m2 - mn);
        m = mn;
        diag += d2;
    }
    if (lane == 0) unsafeAtomicAdd(acc, m + logf(ssum) - diag);
}

__global__ void final_kernel(const float* __restrict__ acc, float* __restrict__ out,
                             float invn, float alpha) {
    out[0] = acc[0] * invn + alpha * invn * (acc[1] + acc[2]);
}

// ================================ driver ==================================

extern "C" void kernel_launch(void* const* d_in, const int* in_sizes, int n_in,
                              void* d_out, int out_size, void* d_ws, size_t ws_size,
                              hipStream_t stream) {
    const float* users_feat   = (const float*)d_in[0];
    const float* bundles_feat = (const float*)d_in[1];
    const float* items_feat   = (const float*)d_in[2];
    const float* W1 = (const float*)d_in[3];
    const float* c1 = (const float*)d_in[4];
    const float* W2 = (const float*)d_in[5];
    const float* c2 = (const float*)d_in[6];
    const float* W3 = (const float*)d_in[7];
    const float* c3 = (const float*)d_in[8];
    const float* ui_val = (const float*)d_in[9];
    const float* ub_val = (const float*)d_in[10];
    const float* bi_val = (const float*)d_in[11];
    const int* ui_row = (const int*)d_in[12];
    const int* ui_col = (const int*)d_in[13];
    const int* ub_row = (const int*)d_in[14];
    const int* ub_col = (const int*)d_in[15];
    const int* bi_row = (const int*)d_in[16];
    const int* bi_col = (const int*)d_in[17];
    const int* uidx = (const int*)d_in[18];
    const int* bidx = (const int*)d_in[19];

    const int U  = in_sizes[0] / DD;
    const int NB = in_sizes[1] / DD;
    const int I  = in_sizes[2] / DD;
    const int Eui = in_sizes[9];
    const int Eub = in_sizes[10];
    const int Ebi = in_sizes[11];
    const int BT = in_sizes[18];

    float* w = (float*)d_ws;
    size_t o = 0;
    float* bufA = w + o; o += (size_t)U * DD;
    float* bufB = w + o; o += (size_t)I * DD;
    float* u1   = w + o; o += (size_t)U * DD;
    float* i1   = w + o; o += (size_t)I * DD;
    float* b1   = w + o; o += (size_t)NB * DD;
    float* u2   = w + o; o += (size_t)U * DD;
    float* b2   = w + o; o += (size_t)NB * DD;
    float* u3b  = w + o; o += (size_t)BT * DD;
    float* A1   = w + o; o += (size_t)BT * DD;
    float* A2   = w + o; o += (size_t)BT * DD;
    float* B1n  = w + o; o += (size_t)BT * DD;
    float* B2n  = w + o; o += (size_t)BT * DD;
    float* acc  = w + o; o += 4;
    // CSR area
    int* ib = (int*)(w + o);
    size_t io_ = 0;
    int* cnt      = ib + io_; io_ += (size_t)U + 2;          // cursor/hist scratch (max dim)
    int* ptr_ui_r = ib + io_; io_ += (size_t)U + 1;
    int* ptr_ui_c = ib + io_; io_ += (size_t)I + 1;
    int* ptr_ub_r = ib + io_; io_ += (size_t)U + 1;
    int* ptr_ub_c = ib + io_; io_ += (size_t)NB + 1;
    int* ptr_bi_r = ib + io_; io_ += (size_t)NB + 1;
    io_ += io_ & 1;  // align pairs to 8B
    int2* pr_ui_r = (int2*)(ib + io_); io_ += (size_t)Eui * 2;
    int2* pr_ui_c = (int2*)(ib + io_); io_ += (size_t)Eui * 2;
    int2* pr_ub_r = (int2*)(ib + io_); io_ += (size_t)Eub * 2;
    int2* pr_ub_c = (int2*)(ib + io_); io_ += (size_t)Eub * 2;
    int2* pr_bi_r = (int2*)(ib + io_); io_ += (size_t)Ebi * 2;
    size_t needed = o * sizeof(float) + io_ * sizeof(int);

    const size_t Ub  = (size_t)U * DD * sizeof(float);
    const size_t Ib  = (size_t)I * DD * sizeof(float);
    const size_t NBb = (size_t)NB * DD * sizeof(float);

    auto avg3 = [&](float* io2, const float* a, const float* b, long long n) {
        long long n4 = n / 4;
        long long nb_ = (n4 + 255) / 256;
        int blocks = (int)(nb_ > 4096 ? 4096 : nb_);
        avg3_kernel<<<blocks, 256, 0, stream>>>((float4*)io2, (const float4*)a,
                                                (const float4*)b, n4);
    };

    if (ws_size >= needed) {
        // ---------------- CSR path (no float atomics) ----------------
        auto build_csr = [&](int2* pairs, int* ptr, const int* tgt, const int* src,
                             const float* val, int n, int E) {
            hipMemsetAsync(cnt, 0, ((size_t)n + 1) * sizeof(int), stream);
            int gb = (E + 255) / 256; if (gb > 4096) gb = 4096;
            hist_kernel<<<gb, 256, 0, stream>>>(cnt, tgt, E);
            scan_kernel<<<1, 1024, 0, stream>>>(ptr, cnt, n);
            copy_int_kernel<<<(n + 255) / 256, 256, 0, stream>>>(cnt, ptr, n);
            scatter_kernel<<<gb, 256, 0, stream>>>(pairs, cnt, tgt, src, val, E);
        };
        auto spmm = [&](float* out_, const float* in_, const int2* pairs, const int* ptr,
                        int nrows) {
            int blocks = (nrows + 3) / 4;  // 4 waves per 256-thread block
            spmm_csr_kernel<<<blocks, 256, 0, stream>>>(out_, in_, pairs, ptr, nrows);
        };

        build_csr(pr_ui_r, ptr_ui_r, ui_row, ui_col, ui_val, U, Eui);
        build_csr(pr_ui_c, ptr_ui_c, ui_col, ui_row, ui_val, I, Eui);
        build_csr(pr_ub_r, ptr_ub_r, ub_row, ub_col, ub_val, U, Eub);
        build_csr(pr_ub_c, ptr_ub_c, ub_col, ub_row, ub_val, NB, Eub);
        build_csr(pr_bi_r, ptr_bi_r, bi_row, bi_col, bi_val, NB, Ebi);

        // ---- View 1: u-i propagation ----
        spmm(bufA, items_feat, pr_ui_r, ptr_ui_r, U);    // x1a (== full u3)
        spmm(bufB, users_feat, pr_ui_c, ptr_ui_c, I);    // x1b
        spmm(u1, bufB, pr_ui_r, ptr_ui_r, U);            // x2a
        spmm(i1, bufA, pr_ui_c, ptr_ui_c, I);            // x2b
        {
            int nthr = BT * DD;
            gather_kernel<<<(nthr + 255) / 256, 256, 0, stream>>>(u3b, bufA, uidx, BT);
        }
        avg3(u1, users_feat, bufA, (long long)U * DD);
        avg3(i1, items_feat, bufB, (long long)I * DD);
        spmm(b1, i1, pr_bi_r, ptr_bi_r, NB);             // b1

        // ---- View 2: u-b propagation ----
        spmm(bufA, bundles_feat, pr_ub_r, ptr_ub_r, U);  // y1a
        spmm(bufB, users_feat, pr_ub_c, ptr_ub_c, NB);   // y1b (NB rows of I-sized buf)
        spmm(u2, bufB, pr_ub_r, ptr_ub_r, U);            // y2a
        spmm(b2, bufA, pr_ub_c, ptr_ub_c, NB);           // y2b
        avg3(u2, users_feat, bufA, (long long)U * DD);
        avg3(b2, bundles_feat, bufB, (long long)NB * DD);

        // ---- View 3: b3 ----
        spmm(bufB, items_feat, pr_bi_r, ptr_bi_r, NB);   // b3 -> bufB
    } else {
        // ---------------- fallback: atomic path ----------------
        auto spmm = [&](float* out_, const float* in_, const int* tgt, const int* src,
                        const float* val, int E) {
            long long nwork = (long long)E * 16;
            long long nb_ = (nwork + 255) / 256;
            int blocks = (int)(nb_ > 16384 ? 16384 : nb_);
            spmm_kernel<<<blocks, 256, 0, stream>>>(out_, in_, tgt, src, val, nwork);
        };
        hipMemsetAsync(bufA, 0, Ub, stream);
        hipMemsetAsync(bufB, 0, Ib, stream);
        hipMemsetAsync(u1, 0, Ub, stream);
        hipMemsetAsync(i1, 0, Ib, stream);
        spmm(bufA, items_feat, ui_row, ui_col, ui_val, Eui);
        spmm(bufB, users_feat, ui_col, ui_row, ui_val, Eui);
        spmm(u1, bufB, ui_row, ui_col, ui_val, Eui);
        spmm(i1, bufA, ui_col, ui_row, ui_val, Eui);
        {
            int nthr = BT * DD;
            gather_kernel<<<(nthr + 255) / 256, 256, 0, stream>>>(u3b, bufA, uidx, BT);
        }
        avg3(u1, users_feat, bufA, (long long)U * DD);
        avg3(i1, items_feat, bufB, (long long)I * DD);
        hipMemsetAsync(b1, 0, NBb, stream);
        spmm(b1, i1, bi_row, bi_col, bi_val, Ebi);
        hipMemsetAsync(bufA, 0, Ub, stream);
        hipMemsetAsync(bufB, 0, NBb, stream);
        spmm(bufA, bundles_feat, ub_row, ub_col, ub_val, Eub);
        spmm(bufB, users_feat, ub_col, ub_row, ub_val, Eub);
        hipMemsetAsync(u2, 0, Ub, stream);
        hipMemsetAsync(b2, 0, NBb, stream);
        spmm(u2, bufB, ub_row, ub_col, ub_val, Eub);
        spmm(b2, bufA, ub_col, ub_row, ub_val, Eub);
        avg3(u2, users_feat, bufA, (long long)U * DD);
        avg3(b2, bundles_feat, bufB, (long long)NB * DD);
        hipMemsetAsync(bufB, 0, NBb, stream);
        spmm(bufB, items_feat, bi_row, bi_col, bi_val, Ebi);
    }

    // ---- batch gathers + normalized views for InfoNCE ----
    gather_norm_kernel<<<BT, 64, 0, stream>>>(A1, u1, uidx, BT, 1);
    gather_norm_kernel<<<BT, 64, 0, stream>>>(A2, u2, uidx, BT, 1);
    gather_norm_kernel<<<BT, 64, 0, stream>>>(B1n, b1, bidx, BT, 2);
    gather_norm_kernel<<<BT, 64, 0, stream>>>(B2n, b2, bidx, BT, 2);

    hipMemsetAsync(acc, 0, 4 * sizeof(float), stream);

    batch_pred_kernel<<<BT, 64, 0, stream>>>(u1, u2, u3b, b1, b2, bufB, uidx, bidx,
                                             W1, c1, W2, c2, W3, c3, acc, BT);

    nce_kernel<<<BT / 4, 256, 0, stream>>>(A1, A2, acc + 1, BT, 4.0f);
    nce_kernel<<<BT / 4, 256, 0, stream>>>(B1n, B2n, acc + 2, BT, 4.0f);

    final_kernel<<<1, 1, 0, stream>>>(acc, (float*)d_out, 1.0f / (float)BT, 0.5f);
}

// Round 3
// 7170.405 us; speedup vs baseline: 3.4574x; 3.4566x over previous
//
#include <hip/hip_runtime.h>
#include <math.h>

#define DD 64

// ============================ CSR build kernels ============================

__global__ void hist_kernel(int* __restrict__ cnt, const int* __restrict__ tgt, int E) {
    int g = blockIdx.x * blockDim.x + threadIdx.x;
    int stride = gridDim.x * blockDim.x;
    for (int e = g; e < E; e += stride) atomicAdd(&cnt[tgt[e]], 1);
}

// exclusive scan of cnt[0..n) -> ptr[0..n], single block of 1024 threads
__global__ void scan_kernel(int* __restrict__ ptr, const int* __restrict__ cnt, int n) {
    __shared__ int part[1024];
    int t = threadIdx.x;
    int per = (n + 1023) / 1024;
    int lo = t * per;
    int hi = lo + per; if (hi > n) hi = n; if (lo > n) lo = n;
    int s = 0;
    for (int i = lo; i < hi; ++i) s += cnt[i];
    part[t] = s;
    __syncthreads();
    for (int off = 1; off < 1024; off <<= 1) {
        int v = (t >= off) ? part[t - off] : 0;
        __syncthreads();
        part[t] += v;
        __syncthreads();
    }
    int run = (t == 0) ? 0 : part[t - 1];
    for (int i = lo; i < hi; ++i) { ptr[i] = run; run += cnt[i]; }
    if (t == 1023) ptr[n] = part[1023];
}

__global__ void copy_int_kernel(int* __restrict__ dst, const int* __restrict__ src, int n) {
    int g = blockIdx.x * blockDim.x + threadIdx.x;
    if (g < n) dst[g] = src[g];
}

// perm[pos] = edge-id grouped by tgt[e]; cursor pre-loaded with ptr
__global__ void scatter_perm_kernel(int* __restrict__ perm, int* __restrict__ cursor,
                                    const int* __restrict__ tgt, int E) {
    int g = blockIdx.x * blockDim.x + threadIdx.x;
    int stride = gridDim.x * blockDim.x;
    for (int e = g; e < E; e += stride) {
        int p = atomicAdd(&cursor[tgt[e]], 1);
        perm[p] = e;
    }
}

// ======================= gather-based segmented SpMM =======================
// one wave per output row; lane = dim; out[r] = sum_{e in row r} val_e * in[src_e]
__global__ void spmm_csr_kernel(float* __restrict__ out, const float* __restrict__ in,
                                const int* __restrict__ perm, const int* __restrict__ ptr,
                                const int* __restrict__ srcarr, const float* __restrict__ valarr,
                                int nrows) {
    int w = (int)(((unsigned)blockIdx.x * blockDim.x + threadIdx.x) >> 6);
    int lane = threadIdx.x & 63;
    if (w >= nrows) return;
    int p = ptr[w];
    int end = ptr[w + 1];
    float a0 = 0.f, a1 = 0.f, a2 = 0.f, a3 = 0.f;
    for (; p + 4 <= end; p += 4) {
        int e0 = __builtin_amdgcn_readfirstlane(perm[p + 0]);
        int e1 = __builtin_amdgcn_readfirstlane(perm[p + 1]);
        int e2 = __builtin_amdgcn_readfirstlane(perm[p + 2]);
        int e3 = __builtin_amdgcn_readfirstlane(perm[p + 3]);
        int s0 = __builtin_amdgcn_readfirstlane(srcarr[e0]);
        int s1 = __builtin_amdgcn_readfirstlane(srcarr[e1]);
        int s2 = __builtin_amdgcn_readfirstlane(srcarr[e2]);
        int s3 = __builtin_amdgcn_readfirstlane(srcarr[e3]);
        float v0 = valarr[e0], v1 = valarr[e1], v2 = valarr[e2], v3 = valarr[e3];
        a0 += v0 * in[(size_t)s0 * DD + lane];
        a1 += v1 * in[(size_t)s1 * DD + lane];
        a2 += v2 * in[(size_t)s2 * DD + lane];
        a3 += v3 * in[(size_t)s3 * DD + lane];
    }
    for (; p < end; ++p) {
        int e0 = __builtin_amdgcn_readfirstlane(perm[p]);
        int s0 = __builtin_amdgcn_readfirstlane(srcarr[e0]);
        a0 += valarr[e0] * in[(size_t)s0 * DD + lane];
    }
    out[(size_t)w * DD + lane] = (a0 + a1) + (a2 + a3);
}

// ===================== fallback atomic SpMM (safety net) =====================
__global__ void spmm_atomic_kernel(float* __restrict__ out, const float* __restrict__ in,
                                   const int* __restrict__ tgt, const int* __restrict__ src,
                                   const float* __restrict__ val, long long nwork) {
    long long g = (long long)blockIdx.x * blockDim.x + threadIdx.x;
    long long stride = (long long)gridDim.x * blockDim.x;
    for (long long t = g; t < nwork; t += stride) {
        int e = (int)(t >> 4);
        int c = (int)(t & 15);
        int s = src[e];
        int dt = tgt[e];
        float v = val[e];
        float4 x = ((const float4*)(in + (size_t)s * DD))[c];
        float* o = out + (size_t)dt * DD + (size_t)c * 4;
        unsafeAtomicAdd(o + 0, v * x.x);
        unsafeAtomicAdd(o + 1, v * x.y);
        unsafeAtomicAdd(o + 2, v * x.z);
        unsafeAtomicAdd(o + 3, v * x.w);
    }
}

// ============================= dense helpers ==============================

__global__ void avg3_kernel(float4* __restrict__ io, const float4* __restrict__ a,
                            const float4* __restrict__ b, long long n4) {
    long long g = (long long)blockIdx.x * blockDim.x + threadIdx.x;
    long long stride = (long long)gridDim.x * blockDim.x;
    const float k = 1.0f / 3.0f;
    for (long long i = g; i < n4; i += stride) {
        float4 x = io[i], y = a[i], z = b[i];
        x.x = (x.x + y.x + z.x) * k;
        x.y = (x.y + y.y + z.y) * k;
        x.z = (x.z + y.z + z.z) * k;
        x.w = (x.w + y.w + z.w) * k;
        io[i] = x;
    }
}

__global__ void gather_kernel(float* __restrict__ out, const float* __restrict__ src,
                              const int* __restrict__ idx, int nrows) {
    int g = blockIdx.x * blockDim.x + threadIdx.x;
    if (g >= nrows * DD) return;
    int r = g >> 6;
    out[g] = src[(size_t)idx[r] * DD + (g & 63)];
}

__global__ void gather_norm_kernel(float* __restrict__ out, const float* __restrict__ src,
                                   const int* __restrict__ idx, int nrows, int istride) {
    int r = blockIdx.x;
    if (r >= nrows) return;
    int d = threadIdx.x;
    float v = src[(size_t)idx[(size_t)r * istride] * DD + d];
    float ss = v * v;
#pragma unroll
    for (int o = 32; o >= 1; o >>= 1) ss += __shfl_xor(ss, o);
    out[(size_t)r * DD + d] = v * rsqrtf(ss + 1e-8f);
}

__global__ void batch_pred_kernel(const float* __restrict__ u1, const float* __restrict__ u2,
                                  const float* __restrict__ u3b,
                                  const float* __restrict__ b1, const float* __restrict__ b2,
                                  const float* __restrict__ b3,
                                  const int* __restrict__ uidx, const int* __restrict__ bidx,
                                  const float* __restrict__ W1, const float* __restrict__ c1,
                                  const float* __restrict__ W2, const float* __restrict__ c2,
                                  const float* __restrict__ W3, const float* __restrict__ c3,
                                  float* __restrict__ acc, int nb) {
    int b = blockIdx.x;
    if (b >= nb) return;
    int d = threadIdx.x;
    int u = uidx[b];
    float ud1 = u1[(size_t)u * DD + d];
    float ud2 = u2[(size_t)u * DD + d];
    float ud3 = u3b[(size_t)b * DD + d];
    float pred[2];
#pragma unroll
    for (int p = 0; p < 2; ++p) {
        int bi = bidx[b * 2 + p];
        float s0 = ud1 * b1[(size_t)bi * DD + d];
        float s1 = ud2 * b2[(size_t)bi * DD + d];
        float s2 = ud3 * b3[(size_t)bi * DD + d];
#pragma unroll
        for (int o = 32; o >= 1; o >>= 1) {
            s0 += __shfl_xor(s0, o);
            s1 += __shfl_xor(s1, o);
            s2 += __shfl_xor(s2, o);
        }
        float t0 = tanhf(s0 * W1[0] + s1 * W1[1] + s2 * W1[2] + c1[0]);
        float t1 = tanhf(s0 * W1[3] + s1 * W1[4] + s2 * W1[5] + c1[1]);
        float t2 = tanhf(s0 * W1[6] + s1 * W1[7] + s2 * W1[8] + c1[2]);
        float g0 = tanhf(t0 * W2[0] + t1 * W2[1] + t2 * W2[2] + c2[0]);
        float g1 = tanhf(t0 * W2[3] + t1 * W2[4] + t2 * W2[5] + c2[1]);
        float g2 = tanhf(t0 * W2[6] + t1 * W2[7] + t2 * W2[8] + c2[2]);
        pred[p] = g0 * W3[0] + g1 * W3[1] + g2 * W3[2] + c3[0];
    }
    if (d == 0) {
        float x = pred[1] - pred[0];
        float sp = (x > 20.0f) ? x : log1pf(expf(x));
        unsafeAtomicAdd(acc, sp);
    }
}

__global__ void nce_kernel(const float* __restrict__ A, const float* __restrict__ B,
                           float* __restrict__ acc, int n, float invtemp) {
    __shared__ float4 a_lds[4][16];
    int wv = threadIdx.x >> 6;
    int lane = threadIdx.x & 63;
    int row = blockIdx.x * 4 + wv;
    if (lane < 16) a_lds[wv][lane] = ((const float4*)(A + (size_t)row * DD))[lane];
    __syncthreads();
    float m = -1e30f, ssum = 0.0f, diag = 0.0f;
    int ntile = n >> 6;
    for (int t = 0; t < ntile; ++t) {
        int j = (t << 6) + lane;
        const float4* Bj = (const float4*)(B + (size_t)j * DD);
        float dot = 0.0f;
#pragma unroll
        for (int q = 0; q < 16; ++q) {
            float4 a4 = a_lds[wv][q];
            float4 b4 = Bj[q];
            dot += a4.x * b4.x + a4.y * b4.y + a4.z * b4.z + a4.w * b4.w;
        }
        float lg = dot * invtemp;
        if (j == row) diag = lg;
        float mn = fmaxf(m, lg);
        ssum = ssum * __expf(m - mn) + __expf(lg - mn);
        m = mn;
    }
#pragma unroll
    for (int o = 32; o >= 1; o >>= 1) {
        float m2 = __shfl_xor(m, o);
        float s2 = __shfl_xor(ssum, o);
        float d2 = __shfl_xor(diag, o);
        float mn = fmaxf(m, m2);
        ssum = ssum * __expf(m - mn) + s2 * __expf(m2 - mn);
        m = mn;
        diag += d2;
    }
    if (lane == 0) unsafeAtomicAdd(acc, m + logf(ssum) - diag);
}

__global__ void final_kernel(const float* __restrict__ acc, float* __restrict__ out,
                             float invn, float alpha) {
    out[0] = acc[0] * invn + alpha * invn * (acc[1] + acc[2]);
}

// ================================ driver ==================================

extern "C" void kernel_launch(void* const* d_in, const int* in_sizes, int n_in,
                              void* d_out, int out_size, void* d_ws, size_t ws_size,
                              hipStream_t stream) {
    const float* users_feat   = (const float*)d_in[0];
    const float* bundles_feat = (const float*)d_in[1];
    const float* items_feat   = (const float*)d_in[2];
    const float* W1 = (const float*)d_in[3];
    const float* c1 = (const float*)d_in[4];
    const float* W2 = (const float*)d_in[5];
    const float* c2 = (const float*)d_in[6];
    const float* W3 = (const float*)d_in[7];
    const float* c3 = (const float*)d_in[8];
    const float* ui_val = (const float*)d_in[9];
    const float* ub_val = (const float*)d_in[10];
    const float* bi_val = (const float*)d_in[11];
    const int* ui_row = (const int*)d_in[12];
    const int* ui_col = (const int*)d_in[13];
    const int* ub_row = (const int*)d_in[14];
    const int* ub_col = (const int*)d_in[15];
    const int* bi_row = (const int*)d_in[16];
    const int* bi_col = (const int*)d_in[17];
    const int* uidx = (const int*)d_in[18];
    const int* bidx = (const int*)d_in[19];

    const int U  = in_sizes[0] / DD;
    const int NB = in_sizes[1] / DD;
    const int I  = in_sizes[2] / DD;
    const int Eui = in_sizes[9];
    const int Eub = in_sizes[10];
    const int Ebi = in_sizes[11];
    const int BT = in_sizes[18];

    const size_t U64  = (size_t)U * DD;
    const size_t I64  = (size_t)I * DD;
    const size_t NB64 = (size_t)NB * DD;
    size_t R2sz = 2 * I64; if (R2sz < U64) R2sz = U64;  // u2 overlays x1b+i1

    // ---------------- float buffer layout (overlaid) ----------------
    float* w = (float*)d_ws;
    size_t o = 0;
    float* T_U1 = w + o; o += U64;    // x1a, then y1a
    float* R2   = w + o; o += R2sz;   // [x1b | i1(x2b)] then u2 (y2a)
    float* T_I1 = R2;                 // x1b / y-scratch
    float* T_I2 = R2 + I64;           // x2b -> i1
    float* u2   = R2;
    float* u1   = w + o; o += U64;    // x2a -> u1
    float* b1   = w + o; o += NB64;
    float* b3   = w + o; o += NB64;
    float* y1b  = w + o; o += NB64;
    float* b2   = w + o; o += NB64;   // y2b -> b2
    float* u3b  = w + o; o += (size_t)BT * DD;
    float* A1   = w + o; o += (size_t)BT * DD;
    float* A2   = w + o; o += (size_t)BT * DD;
    float* B1n  = w + o; o += (size_t)BT * DD;
    float* B2n  = w + o; o += (size_t)BT * DD;
    float* acc  = w + o; o += 16;

    // ---------------- int area: one shared perm/ptr/cnt ----------------
    int nmax = U; if (I > nmax) nmax = I; if (NB > nmax) nmax = NB;
    int emax = Eui; if (Eub > emax) emax = Eub; if (Ebi > emax) emax = Ebi;
    int* ib = (int*)(w + o);
    size_t io_ = 0;
    int* cnt  = ib + io_; io_ += (size_t)nmax + 1;
    int* ptr_ = ib + io_; io_ += (size_t)nmax + 1;
    int* perm = ib + io_; io_ += (size_t)emax;
    size_t needed = o * sizeof(float) + io_ * sizeof(int);

    auto avg3 = [&](float* io2, const float* a, const float* b, long long n) {
        long long n4 = n / 4;
        long long nb_ = (n4 + 255) / 256;
        int blocks = (int)(nb_ > 4096 ? 4096 : nb_);
        avg3_kernel<<<blocks, 256, 0, stream>>>((float4*)io2, (const float4*)a,
                                                (const float4*)b, n4);
    };

    if (ws_size >= needed) {
        // ---------------- CSR gather path (no float atomics) ----------------
        auto build = [&](const int* tgt, int n, int E) {
            hipMemsetAsync(cnt, 0, ((size_t)n + 1) * sizeof(int), stream);
            int gb = (E + 255) / 256; if (gb > 4096) gb = 4096;
            hist_kernel<<<gb, 256, 0, stream>>>(cnt, tgt, E);
            scan_kernel<<<1, 1024, 0, stream>>>(ptr_, cnt, n);
            copy_int_kernel<<<(n + 255) / 256, 256, 0, stream>>>(cnt, ptr_, n);
            scatter_perm_kernel<<<gb, 256, 0, stream>>>(perm, cnt, tgt, E);
        };
        auto spmm = [&](float* out_, const float* in_, const int* srcarr,
                        const float* valarr, int nrows) {
            int blocks = (nrows + 3) / 4;  // 4 waves / block
            spmm_csr_kernel<<<blocks, 256, 0, stream>>>(out_, in_, perm, ptr_,
                                                        srcarr, valarr, nrows);
        };

        // ---- View 1 (u-i), u3 == x1a ----
        build(ui_row, U, Eui);                           // CSR by user
        spmm(T_U1, items_feat, ui_col, ui_val, U);       // x1a
        build(ui_col, I, Eui);                           // CSR by item
        spmm(T_I1, users_feat, ui_row, ui_val, I);       // x1b
        spmm(T_I2, T_U1, ui_row, ui_val, I);             // x2b (reads x1a)
        build(ui_row, U, Eui);                           // rebuild by user
        spmm(u1, T_I1, ui_col, ui_val, U);               // x2a (reads x1b)
        gather_kernel<<<(BT * DD + 255) / 256, 256, 0, stream>>>(u3b, T_U1, uidx, BT);
        avg3(u1, users_feat, T_U1, (long long)U64);      // u1
        avg3(T_I2, items_feat, T_I1, (long long)I64);    // i1 (in T_I2)
        build(bi_row, NB, Ebi);
        spmm(b1, T_I2, bi_col, bi_val, NB);              // b1
        spmm(b3, items_feat, bi_col, bi_val, NB);        // b3

        // ---- View 2 (u-b) ----
        build(ub_row, U, Eub);
        spmm(T_U1, bundles_feat, ub_col, ub_val, U);     // y1a
        build(ub_col, NB, Eub);
        spmm(y1b, users_feat, ub_row, ub_val, NB);       // y1b
        spmm(b2, T_U1, ub_row, ub_val, NB);              // y2b (reads y1a)
        build(ub_row, U, Eub);
        spmm(u2, y1b, ub_col, ub_val, U);                // y2a -> u2 (overlays x1b/i1)
        avg3(u2, users_feat, T_U1, (long long)U64);      // u2
        avg3(b2, bundles_feat, y1b, (long long)NB64);    // b2
    } else {
        // ---------------- atomic fallback (same buffer plan) ----------------
        auto spmm_at = [&](float* out_, const float* in_, const int* tgt, const int* src,
                           const float* val, int E, size_t outfloats) {
            hipMemsetAsync(out_, 0, outfloats * sizeof(float), stream);
            long long nwork = (long long)E * 16;
            long long nb_ = (nwork + 255) / 256;
            int blocks = (int)(nb_ > 16384 ? 16384 : nb_);
            spmm_atomic_kernel<<<blocks, 256, 0, stream>>>(out_, in_, tgt, src, val, nwork);
        };
        spmm_at(T_U1, items_feat, ui_row, ui_col, ui_val, Eui, U64);     // x1a
        spmm_at(T_I1, users_feat, ui_col, ui_row, ui_val, Eui, I64);     // x1b
        spmm_at(T_I2, T_U1, ui_col, ui_row, ui_val, Eui, I64);           // x2b
        spmm_at(u1, T_I1, ui_row, ui_col, ui_val, Eui, U64);             // x2a
        gather_kernel<<<(BT * DD + 255) / 256, 256, 0, stream>>>(u3b, T_U1, uidx, BT);
        avg3(u1, users_feat, T_U1, (long long)U64);
        avg3(T_I2, items_feat, T_I1, (long long)I64);
        spmm_at(b1, T_I2, bi_row, bi_col, bi_val, Ebi, NB64);
        spmm_at(b3, items_feat, bi_row, bi_col, bi_val, Ebi, NB64);
        spmm_at(T_U1, bundles_feat, ub_row, ub_col, ub_val, Eub, U64);   // y1a
        spmm_at(y1b, users_feat, ub_col, ub_row, ub_val, Eub, NB64);     // y1b
        spmm_at(b2, T_U1, ub_col, ub_row, ub_val, Eub, NB64);            // y2b
        spmm_at(u2, y1b, ub_row, ub_col, ub_val, Eub, U64);              // y2a
        avg3(u2, users_feat, T_U1, (long long)U64);
        avg3(b2, bundles_feat, y1b, (long long)NB64);
    }

    // ---- batch gathers + normalized views for InfoNCE ----
    gather_norm_kernel<<<BT, 64, 0, stream>>>(A1, u1, uidx, BT, 1);
    gather_norm_kernel<<<BT, 64, 0, stream>>>(A2, u2, uidx, BT, 1);
    gather_norm_kernel<<<BT, 64, 0, stream>>>(B1n, b1, bidx, BT, 2);
    gather_norm_kernel<<<BT, 64, 0, stream>>>(B2n, b2, bidx, BT, 2);

    hipMemsetAsync(acc, 0, 4 * sizeof(float), stream);

    batch_pred_kernel<<<BT, 64, 0, stream>>>(u1, u2, u3b, b1, b2, b3, uidx, bidx,
                                             W1, c1, W2, c2, W3, c3, acc, BT);

    nce_kernel<<<BT / 4, 256, 0, stream>>>(A1, A2, acc + 1, BT, 4.0f);
    nce_kernel<<<BT / 4, 256, 0, stream>>>(B1n, B2n, acc + 2, BT, 4.0f);

    final_kernel<<<1, 1, 0, stream>>>(acc, (float*)d_out, 1.0f / (float)BT, 0.5f);
}